// Round 1
// baseline (208.684 us; speedup 1.0000x reference)
//
#include <hip/hip_runtime.h>
#include <math.h>

#define NQ 8
#define DEPTH 6

// Complex 2x2 gate matrix (row-major: u00 u01 / u10 u11), split re/im.
struct C2x2 {
    float r00, i00, r01, i01, r10, i10, r11, i11;
};

// ---- single-qubit gate on a register-local qubit pair (compile-time indices) ----
#define PAIR_APPLY(i0, i1)                                                     \
    {                                                                          \
        float x0r = ar[i0], x0i = ai[i0], x1r = ar[i1], x1i = ai[i1];          \
        ar[i0] = u.r00 * x0r - u.i00 * x0i + u.r01 * x1r - u.i01 * x1i;        \
        ai[i0] = u.r00 * x0i + u.i00 * x0r + u.r01 * x1i + u.i01 * x1r;        \
        ar[i1] = u.r10 * x0r - u.i10 * x0i + u.r11 * x1r - u.i11 * x1i;        \
        ai[i1] = u.r10 * x0i + u.i10 * x0r + u.r11 * x1i + u.i11 * x1r;        \
    }

// General single-qubit gate on qubit q (0..7). Qubits 0,1 = local bits of the
// 4 amplitudes per lane; qubits 2..7 = lane bits (shfl_xor partner exchange).
__device__ __forceinline__ void apply1(float (&ar)[4], float (&ai)[4],
                                       int lane, int q, const C2x2 u)
{
    if (q == 0) {
        PAIR_APPLY(0, 1);
        PAIR_APPLY(2, 3);
    } else if (q == 1) {
        PAIR_APPLY(0, 2);
        PAIR_APPLY(1, 3);
    } else {
        const int xm  = 1 << (q - 2);
        const int bit = (lane >> (q - 2)) & 1;
        // row b of U: self-coef = U[b][b], partner-coef = U[b][1-b]
        const float sr = bit ? u.r11 : u.r00;
        const float si = bit ? u.i11 : u.i00;
        const float pr_c = bit ? u.r10 : u.r01;
        const float pi_c = bit ? u.i10 : u.i01;
#pragma unroll
        for (int i = 0; i < 4; i++) {
            float pr = __shfl_xor(ar[i], xm);
            float pi = __shfl_xor(ai[i], xm);
            float nr = sr * ar[i] - si * ai[i] + pr_c * pr - pi_c * pi;
            float ni = sr * ai[i] + si * ar[i] + pr_c * pi + pi_c * pr;
            ar[i] = nr;
            ai[i] = ni;
        }
    }
}

// Diagonal gate diag(d0, d1) on qubit q — shuffle-free for any q.
__device__ __forceinline__ void applyDiag(float (&ar)[4], float (&ai)[4],
                                          int lane, int q,
                                          float d0r, float d0i,
                                          float d1r, float d1i)
{
#pragma unroll
    for (int i = 0; i < 4; i++) {
        int g   = (lane << 2) | i;
        int bit = (g >> q) & 1;
        float dr = bit ? d1r : d0r;
        float di = bit ? d1i : d0i;
        float nr = dr * ar[i] - di * ai[i];
        float ni = dr * ai[i] + di * ar[i];
        ar[i] = nr;
        ai[i] = ni;
    }
}

// CZ(c,t): sign flip where both bits set. Shuffle-free.
__device__ __forceinline__ void applyCZ(float (&ar)[4], float (&ai)[4],
                                        int lane, int c, int t)
{
#pragma unroll
    for (int i = 0; i < 4; i++) {
        int g = (lane << 2) | i;
        if ((g >> c) & (g >> t) & 1) {
            ar[i] = -ar[i];
            ai[i] = -ai[i];
        }
    }
}

// select pr[j] / pq[j] with runtime j in 0..3 without scratch spill
#define SEL4(arr, j) ((j) == 0 ? arr[0] : (j) == 1 ? arr[1] : (j) == 2 ? arr[2] : arr[3])

// Controlled-X: new[g] = old[g ^ (1<<t)] when (g & cm) == cm.
// Handles CNOT (cm = one control bit) and Toffoli (cm = two control bits).
__device__ __forceinline__ void applyCX(float (&ar)[4], float (&ai)[4],
                                        int lane, int cm, int t)
{
    const int m        = 1 << t;
    const int laneXor  = m >> 2;
    const int localXor = m & 3;
    float pr[4], pq[4];
#pragma unroll
    for (int i = 0; i < 4; i++) {
        pr[i] = __shfl_xor(ar[i], laneXor);   // laneXor==0 -> self
        pq[i] = __shfl_xor(ai[i], laneXor);
    }
#pragma unroll
    for (int i = 0; i < 4; i++) {
        int g    = (lane << 2) | i;
        bool cnd = (g & cm) == cm;
        int j    = i ^ localXor;
        float sr = SEL4(pr, j);
        float si = SEL4(pq, j);
        if (cnd) { ar[i] = sr; ai[i] = si; }
    }
}

// CSWAP(c; t1,t2): swap bits t1,t2 when control c set.
// new[g] = old[g ^ (1<<t1) ^ (1<<t2)] when bit_c(g) && bit_t1(g)!=bit_t2(g).
__device__ __forceinline__ void applyCSWAP(float (&ar)[4], float (&ai)[4],
                                           int lane, int c, int t1, int t2)
{
    const int m        = (1 << t1) | (1 << t2);
    const int laneXor  = m >> 2;
    const int localXor = m & 3;
    float pr[4], pq[4];
#pragma unroll
    for (int i = 0; i < 4; i++) {
        pr[i] = __shfl_xor(ar[i], laneXor);
        pq[i] = __shfl_xor(ai[i], laneXor);
    }
#pragma unroll
    for (int i = 0; i < 4; i++) {
        int g    = (lane << 2) | i;
        bool cnd = (((g >> c) & 1) != 0) && ((((g >> t1) ^ (g >> t2)) & 1) != 0);
        int j    = i ^ localXor;
        float sr = SEL4(pr, j);
        float si = SEL4(pq, j);
        if (cnd) { ar[i] = sr; ai[i] = si; }
    }
}

__global__ __launch_bounds__(256) void qsim_kernel(
    const float* __restrict__ feats,    // [B, 8]
    const float* __restrict__ qparams,  // [48] = (6,8)
    const int* __restrict__ d_ry,       // [24] = (6,4)
    const int* __restrict__ d_rot,      // [24]
    const int* __restrict__ d_g2,       // [24]
    float* __restrict__ out,            // [B, 8]
    int B)
{
    const int lane = threadIdx.x & 63;
    const int b    = (int)((blockIdx.x * blockDim.x + threadIdx.x) >> 6);
    if (b >= B) return;

    // H^8 |0> = uniform state, amplitude 1/16 everywhere.
    float ar[4], ai[4];
#pragma unroll
    for (int i = 0; i < 4; i++) { ar[i] = 0.0625f; ai[i] = 0.0f; }

    for (int layer = 0; layer < DEPTH; layer++) {
        for (int node = 0; node < NQ; node++) {
            const int di = layer * 4 + (node & 3);

            // 1) per-sample RY(feats[b, node])
            if (d_ry[di]) {
                float th = feats[(size_t)b * NQ + node];
                float s, c;
                __sincosf(th * 0.5f, &s, &c);
                C2x2 u = { c, 0.f, -s, 0.f, s, 0.f, c, 0.f };
                apply1(ar, ai, lane, node, u);
            }

            // 2) trainable rotation RX/RY/RZ (rot==3 -> none)
            int rot = d_rot[di];
            if (rot < 3) {
                float th = qparams[layer * NQ + node];
                float s, c;
                __sincosf(th * 0.5f, &s, &c);
                if (rot == 0) {          // RX: [[c, -is], [-is, c]]
                    C2x2 u = { c, 0.f, 0.f, -s, 0.f, -s, c, 0.f };
                    apply1(ar, ai, lane, node, u);
                } else if (rot == 1) {   // RY: [[c, -s], [s, c]]
                    C2x2 u = { c, 0.f, -s, 0.f, s, 0.f, c, 0.f };
                    apply1(ar, ai, lane, node, u);
                } else {                 // RZ: diag(c - is, c + is)
                    applyDiag(ar, ai, lane, node, c, -s, c, s);
                }
            }

            // 3) entangling / extra gate
            int g2 = d_g2[di];
            if (g2 != 0) {
                int n1 = (node + 1) & 7;
                int n2 = (node + 2) & 7;
                switch (g2) {
                    case 1: {  // H
                        const float r = 0.70710678118654752f;
                        C2x2 u = { r, 0.f, r, 0.f, r, 0.f, -r, 0.f };
                        apply1(ar, ai, lane, node, u);
                    } break;
                    case 2: {  // PauliX
                        C2x2 u = { 0.f, 0.f, 1.f, 0.f, 1.f, 0.f, 0.f, 0.f };
                        apply1(ar, ai, lane, node, u);
                    } break;
                    case 3: {  // PauliY: [[0,-i],[i,0]]
                        C2x2 u = { 0.f, 0.f, 0.f, -1.f, 0.f, 1.f, 0.f, 0.f };
                        apply1(ar, ai, lane, node, u);
                    } break;
                    case 4:    // PauliZ
                        applyDiag(ar, ai, lane, node, 1.f, 0.f, -1.f, 0.f);
                        break;
                    case 5:    // CNOT(node -> node+1)
                        applyCX(ar, ai, lane, 1 << node, n1);
                        break;
                    case 6:    // CSWAP(node; node+1, node+2)
                        applyCSWAP(ar, ai, lane, node, n1, n2);
                        break;
                    case 7:    // Toffoli(node, node+1 -> node+2)
                        applyCX(ar, ai, lane, (1 << node) | (1 << n1), n2);
                        break;
                    case 8:    // CZ(node, node+1)
                        applyCZ(ar, ai, lane, node, n1);
                        break;
                    default: break;
                }
            }
        }
    }

    // ---- expectation values <Z_q> = P(bit_q=0) - P(bit_q=1) ----
    float p[4];
#pragma unroll
    for (int i = 0; i < 4; i++) p[i] = ar[i] * ar[i] + ai[i] * ai[i];

    float ex[8];
    ex[0] = (p[0] - p[1]) + (p[2] - p[3]);   // qubit 0 = local bit 0
    ex[1] = (p[0] + p[1]) - (p[2] + p[3]);   // qubit 1 = local bit 1
    float tot = p[0] + p[1] + p[2] + p[3];
#pragma unroll
    for (int q = 2; q < 8; q++)
        ex[q] = ((lane >> (q - 2)) & 1) ? -tot : tot;

#pragma unroll
    for (int q = 0; q < 8; q++) {
#pragma unroll
        for (int d = 1; d < 64; d <<= 1)
            ex[q] += __shfl_xor(ex[q], d);
    }

    if (lane == 0) {
#pragma unroll
        for (int q = 0; q < 8; q++)
            out[(size_t)b * NQ + q] = ex[q];
    }
}

extern "C" void kernel_launch(void* const* d_in, const int* in_sizes, int n_in,
                              void* d_out, int out_size, void* d_ws, size_t ws_size,
                              hipStream_t stream)
{
    (void)n_in; (void)out_size; (void)d_ws; (void)ws_size;
    const float* feats   = (const float*)d_in[0];
    const float* qparams = (const float*)d_in[1];
    const int* dry       = (const int*)d_in[2];
    const int* drot      = (const int*)d_in[3];
    const int* dg2       = (const int*)d_in[4];
    float* out           = (float*)d_out;

    const int B = in_sizes[0] / NQ;          // 16384
    const int waves  = B;                    // one wave per batch element
    const int blocks = (waves * 64 + 255) / 256;
    qsim_kernel<<<blocks, 256, 0, stream>>>(feats, qparams, dry, drot, dg2, out, B);
}

// Round 2
// 164.844 us; speedup vs baseline: 1.2659x; 1.2659x over previous
//
#include <hip/hip_runtime.h>
#include <math.h>

#define NQ 8

// ---------- lane exchange helper: compile-time xor mask, 0 => identity ----------
template<int XM>
__device__ __forceinline__ float sx(float v) {
    if constexpr (XM == 0) return v;
    else return __shfl_xor(v, XM, 64);
}

// ---------- real 2x2 [[a,b],[d,e]] on qubit Q (compile-time) ----------
__device__ __forceinline__ void realPair(float& x0r, float& x0i, float& x1r, float& x1i,
                                         float a, float b, float d, float e)
{
    float n0r = a * x0r + b * x1r, n0i = a * x0i + b * x1i;
    float n1r = d * x0r + e * x1r, n1i = d * x0i + e * x1i;
    x0r = n0r; x0i = n0i; x1r = n1r; x1i = n1i;
}

template<int Q>
__device__ __forceinline__ void realGate(float (&ar)[4], float (&ai)[4], int lane,
                                         float a, float b, float d, float e)
{
    if constexpr (Q == 0) {
        realPair(ar[0], ai[0], ar[1], ai[1], a, b, d, e);
        realPair(ar[2], ai[2], ar[3], ai[3], a, b, d, e);
    } else if constexpr (Q == 1) {
        realPair(ar[0], ai[0], ar[2], ai[2], a, b, d, e);
        realPair(ar[1], ai[1], ar[3], ai[3], a, b, d, e);
    } else {
        constexpr int XM = 1 << (Q - 2);
        const int bit = (lane >> (Q - 2)) & 1;
        const float sc = bit ? e : a;   // self coefficient
        const float pc = bit ? d : b;   // partner coefficient
#pragma unroll
        for (int i = 0; i < 4; i++) {
            float pr = sx<XM>(ar[i]);
            float pi = sx<XM>(ai[i]);
            ar[i] = sc * ar[i] + pc * pr;
            ai[i] = sc * ai[i] + pc * pi;
        }
    }
}

// ---------- RX: [[c, -i s], [-i s, c]] ----------
__device__ __forceinline__ void rxPair(float& x0r, float& x0i, float& x1r, float& x1i,
                                       float c, float s)
{
    float n0r = c * x0r + s * x1i, n0i = c * x0i - s * x1r;
    float n1r = c * x1r + s * x0i, n1i = c * x1i - s * x0r;
    x0r = n0r; x0i = n0i; x1r = n1r; x1i = n1i;
}

template<int Q>
__device__ __forceinline__ void applyRX(float (&ar)[4], float (&ai)[4], int lane,
                                        float c, float s)
{
    if constexpr (Q == 0) {
        rxPair(ar[0], ai[0], ar[1], ai[1], c, s);
        rxPair(ar[2], ai[2], ar[3], ai[3], c, s);
    } else if constexpr (Q == 1) {
        rxPair(ar[0], ai[0], ar[2], ai[2], c, s);
        rxPair(ar[1], ai[1], ar[3], ai[3], c, s);
    } else {
        constexpr int XM = 1 << (Q - 2);
#pragma unroll
        for (int i = 0; i < 4; i++) {
            float pr = sx<XM>(ar[i]);
            float pi = sx<XM>(ai[i]);
            float nr = c * ar[i] + s * pi;
            float ni = c * ai[i] - s * pr;
            ar[i] = nr; ai[i] = ni;
        }
    }
}

// ---------- RZ: diag(c - i s, c + i s) — shuffle-free ----------
template<int Q>
__device__ __forceinline__ void applyRZ(float (&ar)[4], float (&ai)[4], int lane,
                                        float c, float s)
{
#pragma unroll
    for (int i = 0; i < 4; i++) {
        int bit;
        if constexpr (Q < 2) bit = (i >> Q) & 1;
        else                 bit = (lane >> (Q - 2)) & 1;
        float t = bit ? -s : s;
        float nr = c * ar[i] + t * ai[i];
        float ni = c * ai[i] - t * ar[i];
        ar[i] = nr; ai[i] = ni;
    }
}

// ---------- Pauli Z ----------
template<int Q>
__device__ __forceinline__ void applyZ(float (&ar)[4], float (&ai)[4], int lane)
{
#pragma unroll
    for (int i = 0; i < 4; i++) {
        int bit;
        if constexpr (Q < 2) bit = (i >> Q) & 1;
        else                 bit = (lane >> (Q - 2)) & 1;
        ar[i] = bit ? -ar[i] : ar[i];
        ai[i] = bit ? -ai[i] : ai[i];
    }
}

// ---------- Pauli X: pure permutation ----------
__device__ __forceinline__ void swapf(float& a, float& b) { float t = a; a = b; b = t; }

template<int Q>
__device__ __forceinline__ void applyX(float (&ar)[4], float (&ai)[4], int lane)
{
    if constexpr (Q == 0) {
        swapf(ar[0], ar[1]); swapf(ai[0], ai[1]);
        swapf(ar[2], ar[3]); swapf(ai[2], ai[3]);
    } else if constexpr (Q == 1) {
        swapf(ar[0], ar[2]); swapf(ai[0], ai[2]);
        swapf(ar[1], ar[3]); swapf(ai[1], ai[3]);
    } else {
        constexpr int XM = 1 << (Q - 2);
#pragma unroll
        for (int i = 0; i < 4; i++) {
            ar[i] = sx<XM>(ar[i]);
            ai[i] = sx<XM>(ai[i]);
        }
    }
}

// ---------- Pauli Y: new[g, bit=0] = (p_i, -p_r), new[g, bit=1] = (-p_i, p_r) ----------
__device__ __forceinline__ void yPair(float& x0r, float& x0i, float& x1r, float& x1i)
{
    float n0r = x1i, n0i = -x1r;
    float n1r = -x0i, n1i = x0r;
    x0r = n0r; x0i = n0i; x1r = n1r; x1i = n1i;
}

template<int Q>
__device__ __forceinline__ void applyY(float (&ar)[4], float (&ai)[4], int lane)
{
    if constexpr (Q == 0) {
        yPair(ar[0], ai[0], ar[1], ai[1]);
        yPair(ar[2], ai[2], ar[3], ai[3]);
    } else if constexpr (Q == 1) {
        yPair(ar[0], ai[0], ar[2], ai[2]);
        yPair(ar[1], ai[1], ar[3], ai[3]);
    } else {
        constexpr int XM = 1 << (Q - 2);
        const int bit = (lane >> (Q - 2)) & 1;
#pragma unroll
        for (int i = 0; i < 4; i++) {
            float pr = sx<XM>(ar[i]);
            float pi = sx<XM>(ai[i]);
            ar[i] = bit ? -pi : pi;
            ai[i] = bit ? pr : -pr;
        }
    }
}

// ---------- CZ(C,T): sign flip when both bits set — shuffle-free ----------
template<int C, int T>
__device__ __forceinline__ void applyCZ(float (&ar)[4], float (&ai)[4], int lane)
{
#pragma unroll
    for (int i = 0; i < 4; i++) {
        int g = (lane << 2) | i;
        bool f = (((g >> C) & (g >> T)) & 1) != 0;
        ar[i] = f ? -ar[i] : ar[i];
        ai[i] = f ? -ai[i] : ai[i];
    }
}

// ---------- controlled permutation: new[g] = old[g^M] when (g & CM) == CM ----------
// Handles CNOT (CM = 1 control bit) and Toffoli (CM = 2 control bits). M = single target bit.
template<int CM, int M>
__device__ __forceinline__ void applyCPerm(float (&ar)[4], float (&ai)[4], int lane)
{
    constexpr int LX  = M >> 2;    // lane-xor
    constexpr int PL  = M & 3;     // local-xor
    constexpr int CML = CM & 3;    // control bits in local index
    constexpr int CMH = CM >> 2;   // control bits in lane index
    float tr[4] = { ar[0], ar[1], ar[2], ar[3] };
    float ti[4] = { ai[0], ai[1], ai[2], ai[3] };
#pragma unroll
    for (int i = 0; i < 4; i++) {
        if ((i & CML) == CML) {            // folds: i is constant after unroll
            int j = i ^ PL;
            float srv = sx<LX>(tr[j]);
            float siv = sx<LX>(ti[j]);
            if constexpr (CMH != 0) {
                bool c = (lane & CMH) == CMH;
                ar[i] = c ? srv : ar[i];
                ai[i] = c ? siv : ai[i];
            } else {
                ar[i] = srv; ai[i] = siv;
            }
        }
    }
}

// ---------- CSWAP(C; T1,T2): new[g] = old[g ^ (1<<T1) ^ (1<<T2)] when ctrl && bits differ ----
template<int C, int T1, int T2>
__device__ __forceinline__ void applyCSWAP(float (&ar)[4], float (&ai)[4], int lane)
{
    constexpr int M  = (1 << T1) | (1 << T2);
    constexpr int LX = M >> 2;
    constexpr int PL = M & 3;
    float tr[4] = { ar[0], ar[1], ar[2], ar[3] };
    float ti[4] = { ai[0], ai[1], ai[2], ai[3] };
#pragma unroll
    for (int i = 0; i < 4; i++) {
        int g = (lane << 2) | i;
        bool cnd = (((g >> C) & 1) != 0) && ((((g >> T1) ^ (g >> T2)) & 1) != 0);
        int j = i ^ PL;
        float srv = sx<LX>(tr[j]);
        float siv = sx<LX>(ti[j]);
        ar[i] = cnd ? srv : ar[i];
        ai[i] = cnd ? siv : ai[i];
    }
}

// ---------- one (layer, node) step, fully compile-time indices ----------
template<int I>
__device__ __forceinline__ void allGates(float (&ar)[4], float (&ai)[4], int lane,
                                         const float (&fc)[8], const float (&fs)[8],
                                         const float* __restrict__ qp,
                                         const int* __restrict__ dry,
                                         const int* __restrict__ drot,
                                         const int* __restrict__ dg2)
{
    constexpr int L = I / 8;
    constexpr int N = I % 8;
    constexpr int DI = L * 4 + (N & 3);
    constexpr int N1 = (N + 1) & 7;
    constexpr int N2 = (N + 2) & 7;

    // 1) per-sample RY(feats[b, N]) — sincos hoisted (angle depends only on N)
    if (dry[DI])
        realGate<N>(ar, ai, lane, fc[N], -fs[N], fs[N], fc[N]);

    // 2) trainable rotation
    int rot = drot[DI];
    if (rot < 3) {
        float s, c;
        __sincosf(qp[L * NQ + N] * 0.5f, &s, &c);
        if (rot == 0)      applyRX<N>(ar, ai, lane, c, s);
        else if (rot == 1) realGate<N>(ar, ai, lane, c, -s, s, c);
        else               applyRZ<N>(ar, ai, lane, c, s);
    }

    // 3) entangling / extra gate
    int g2 = dg2[DI];
    if (g2) {
        switch (g2) {
            case 1: {
                const float r = 0.70710678118654752f;
                realGate<N>(ar, ai, lane, r, r, r, -r);
            } break;
            case 2: applyX<N>(ar, ai, lane); break;
            case 3: applyY<N>(ar, ai, lane); break;
            case 4: applyZ<N>(ar, ai, lane); break;
            case 5: applyCPerm<(1 << N), (1 << N1)>(ar, ai, lane); break;
            case 6: applyCSWAP<N, N1, N2>(ar, ai, lane); break;
            case 7: applyCPerm<(1 << N) | (1 << N1), (1 << N2)>(ar, ai, lane); break;
            case 8: applyCZ<N, N1>(ar, ai, lane); break;
            default: break;
        }
    }

    if constexpr (I + 1 < 48)
        allGates<I + 1>(ar, ai, lane, fc, fs, qp, dry, drot, dg2);
}

__global__ __launch_bounds__(256) void qsim_kernel(
    const float* __restrict__ feats,    // [B, 8]
    const float* __restrict__ qp,       // [48]
    const int* __restrict__ dry,        // [24]
    const int* __restrict__ drot,       // [24]
    const int* __restrict__ dg2,        // [24]
    float* __restrict__ out,            // [B, 8]
    int B)
{
    const int lane = threadIdx.x & 63;
    const int b    = (int)((blockIdx.x * blockDim.x + threadIdx.x) >> 6);
    if (b >= B) return;

    // per-node half-angle sincos of features (reused across all 6 layers)
    const float4* f4 = (const float4*)(feats + (size_t)b * NQ);
    float4 fA = f4[0], fB = f4[1];
    float fv[8] = { fA.x, fA.y, fA.z, fA.w, fB.x, fB.y, fB.z, fB.w };
    float fc[8], fs[8];
#pragma unroll
    for (int k = 0; k < 8; k++)
        __sincosf(fv[k] * 0.5f, &fs[k], &fc[k]);

    // H^8 |0> = uniform amplitude 1/16
    float ar[4], ai[4];
#pragma unroll
    for (int i = 0; i < 4; i++) { ar[i] = 0.0625f; ai[i] = 0.0f; }

    allGates<0>(ar, ai, lane, fc, fs, qp, dry, drot, dg2);

    // ---- epilogue: <Z_q> ----
    float p0 = ar[0] * ar[0] + ai[0] * ai[0];
    float p1 = ar[1] * ar[1] + ai[1] * ai[1];
    float p2 = ar[2] * ar[2] + ai[2] * ai[2];
    float p3 = ar[3] * ar[3] + ai[3] * ai[3];

    float e0  = (p0 - p1) + (p2 - p3);   // qubit 0 (local bit 0)
    float e1  = (p0 + p1) - (p2 + p3);   // qubit 1 (local bit 1)
    float tot = p0 + p1 + p2 + p3;       // per-lane probability mass

    // plain wave sums for e0, e1
#pragma unroll
    for (int d = 1; d < 64; d <<= 1) {
        e0 += __shfl_xor(e0, d, 64);
        e1 += __shfl_xor(e1, d, 64);
    }
    // FWHT on tot: after 6 stages, lane (1<<q) holds sum_l (-1)^{bit_q(l)} tot_l = <Z_{q+2}>
#pragma unroll
    for (int d = 1; d < 64; d <<= 1) {
        float p = __shfl_xor(tot, d, 64);
        tot = (lane & d) ? (p - tot) : (p + tot);
    }

    float* ob = out + (size_t)b * NQ;
    if (lane == 0) { ob[0] = e0; ob[1] = e1; }
    if (lane && !(lane & (lane - 1)))            // lanes 1,2,4,8,16,32
        ob[2 + __builtin_ctz(lane)] = tot;
}

extern "C" void kernel_launch(void* const* d_in, const int* in_sizes, int n_in,
                              void* d_out, int out_size, void* d_ws, size_t ws_size,
                              hipStream_t stream)
{
    (void)n_in; (void)out_size; (void)d_ws; (void)ws_size;
    const float* feats   = (const float*)d_in[0];
    const float* qparams = (const float*)d_in[1];
    const int* dry       = (const int*)d_in[2];
    const int* drot      = (const int*)d_in[3];
    const int* dg2       = (const int*)d_in[4];
    float* out           = (float*)d_out;

    const int B = in_sizes[0] / NQ;          // 16384
    const int blocks = (B * 64 + 255) / 256; // one wave per batch element
    qsim_kernel<<<blocks, 256, 0, stream>>>(feats, qparams, dry, drot, dg2, out, B);
}

// Round 3
// 127.203 us; speedup vs baseline: 1.6406x; 1.2959x over previous
//
#include <hip/hip_runtime.h>
#include <math.h>

#define NQ 8

// sin/cos of theta (radians) via raw v_sin/v_cos (input in revolutions).
#define INV2PI 0.15915494309189535f
__device__ __forceinline__ float fsinr(float th) { return __builtin_amdgcn_sinf(th * INV2PI); }
__device__ __forceinline__ float fcosr(float th) { return __builtin_amdgcn_cosf(th * INV2PI); }

// ---- cross-lane xor exchange, compile-time mask (0 => identity). masks <= 15 only ----
template<int XM>
__device__ __forceinline__ float sx(float v) {
    if constexpr (XM == 0) return v;
    else {
        // ds_swizzle BitMode: offset = (xor<<10) | (or<<5) | and ; and=0x1F, or=0
        int r = __builtin_amdgcn_ds_swizzle(__float_as_int(v), (XM << 10) | 0x1F);
        return __int_as_float(r);
    }
}

// Layout: amp index g = i | (laneq<<4); qubit k -> bit k of g.
// Qubits 0..3 = local bits (i), qubits 4..7 = lane bits (laneq).

// ---- real 2x2 [[a,b],[d,e]] on qubit Q ----
template<int Q>
__device__ __forceinline__ void realGate(float (&sr)[16], float (&si)[16], int laneq,
                                         float a, float b, float d, float e)
{
    if constexpr (Q < 4) {
        constexpr int M = 1 << Q;
#pragma unroll
        for (int i = 0; i < 16; i++) if (!(i & M)) {
            const int j = i | M;
            float x0r = sr[i], x0i = si[i], x1r = sr[j], x1i = si[j];
            sr[i] = a * x0r + b * x1r;  si[i] = a * x0i + b * x1i;
            sr[j] = d * x0r + e * x1r;  si[j] = d * x0i + e * x1i;
        }
    } else {
        constexpr int XM = 1 << (Q - 4);
        const int bit = (laneq >> (Q - 4)) & 1;
        const float sc = bit ? e : a;   // self coefficient
        const float pc = bit ? d : b;   // partner coefficient
#pragma unroll
        for (int i = 0; i < 16; i++) {
            float pr = sx<XM>(sr[i]);
            float pi = sx<XM>(si[i]);
            sr[i] = sc * sr[i] + pc * pr;
            si[i] = sc * si[i] + pc * pi;
        }
    }
}

// ---- RX: [[c, -i s], [-i s, c]] ----
template<int Q>
__device__ __forceinline__ void applyRX(float (&sr)[16], float (&si)[16], int laneq,
                                        float c, float s)
{
    if constexpr (Q < 4) {
        constexpr int M = 1 << Q;
#pragma unroll
        for (int i = 0; i < 16; i++) if (!(i & M)) {
            const int j = i | M;
            float x0r = sr[i], x0i = si[i], x1r = sr[j], x1i = si[j];
            sr[i] = c * x0r + s * x1i;  si[i] = c * x0i - s * x1r;
            sr[j] = c * x1r + s * x0i;  si[j] = c * x1i - s * x0r;
        }
    } else {
        constexpr int XM = 1 << (Q - 4);
#pragma unroll
        for (int i = 0; i < 16; i++) {
            float pr = sx<XM>(sr[i]);
            float pi = sx<XM>(si[i]);
            float nr = c * sr[i] + s * pi;
            float ni = c * si[i] - s * pr;
            sr[i] = nr; si[i] = ni;
        }
    }
}

// ---- RZ: diag(c - i s, c + i s) — shuffle-free ----
template<int Q>
__device__ __forceinline__ void applyRZ(float (&sr)[16], float (&si)[16], int laneq,
                                        float c, float s)
{
    if constexpr (Q >= 4) {
        const int bit = (laneq >> (Q - 4)) & 1;
        const float t = bit ? -s : s;
#pragma unroll
        for (int i = 0; i < 16; i++) {
            float nr = c * sr[i] + t * si[i];
            float ni = c * si[i] - t * sr[i];
            sr[i] = nr; si[i] = ni;
        }
    } else {
#pragma unroll
        for (int i = 0; i < 16; i++) {
            const float t = ((i >> Q) & 1) ? -s : s;
            float nr = c * sr[i] + t * si[i];
            float ni = c * si[i] - t * sr[i];
            sr[i] = nr; si[i] = ni;
        }
    }
}

// ---- Pauli Z ----
template<int Q>
__device__ __forceinline__ void applyZ(float (&sr)[16], float (&si)[16], int laneq)
{
    if constexpr (Q >= 4) {
        const bool f = ((laneq >> (Q - 4)) & 1) != 0;
#pragma unroll
        for (int i = 0; i < 16; i++) {
            sr[i] = f ? -sr[i] : sr[i];
            si[i] = f ? -si[i] : si[i];
        }
    } else {
#pragma unroll
        for (int i = 0; i < 16; i++) if ((i >> Q) & 1) {
            sr[i] = -sr[i]; si[i] = -si[i];
        }
    }
}

// ---- Pauli X ----
__device__ __forceinline__ void swapf(float& a, float& b) { float t = a; a = b; b = t; }

template<int Q>
__device__ __forceinline__ void applyX(float (&sr)[16], float (&si)[16], int laneq)
{
    if constexpr (Q < 4) {
        constexpr int M = 1 << Q;
#pragma unroll
        for (int i = 0; i < 16; i++) if (!(i & M)) {
            swapf(sr[i], sr[i | M]); swapf(si[i], si[i | M]);
        }
    } else {
        constexpr int XM = 1 << (Q - 4);
#pragma unroll
        for (int i = 0; i < 16; i++) {
            sr[i] = sx<XM>(sr[i]);
            si[i] = sx<XM>(si[i]);
        }
    }
}

// ---- Pauli Y: [[0,-i],[i,0]] ----
template<int Q>
__device__ __forceinline__ void applyY(float (&sr)[16], float (&si)[16], int laneq)
{
    if constexpr (Q < 4) {
        constexpr int M = 1 << Q;
#pragma unroll
        for (int i = 0; i < 16; i++) if (!(i & M)) {
            const int j = i | M;
            float x0r = sr[i], x0i = si[i], x1r = sr[j], x1i = si[j];
            sr[i] = x1i;  si[i] = -x1r;
            sr[j] = -x0i; si[j] = x0r;
        }
    } else {
        constexpr int XM = 1 << (Q - 4);
        const int bit = (laneq >> (Q - 4)) & 1;
#pragma unroll
        for (int i = 0; i < 16; i++) {
            float pr = sx<XM>(sr[i]);
            float pi = sx<XM>(si[i]);
            sr[i] = bit ? -pi : pi;
            si[i] = bit ? pr : -pr;
        }
    }
}

// ---- CZ(C,T): sign flip when both bits set — shuffle-free ----
template<int C, int T>
__device__ __forceinline__ void applyCZ(float (&sr)[16], float (&si)[16], int laneq)
{
#pragma unroll
    for (int i = 0; i < 16; i++) {
        const int g = i | (laneq << 4);
        const bool f = (((g >> C) & (g >> T)) & 1) != 0;
        sr[i] = f ? -sr[i] : sr[i];
        si[i] = f ? -si[i] : si[i];
    }
}

// ---- controlled permutation: new[g] = old[g ^ M] when (g & CM) == CM ----
// CNOT: CM = 1 control bit. Toffoli: CM = 2 control bits. M = single target bit.
template<int CM, int M>
__device__ __forceinline__ void applyCPerm(float (&sr)[16], float (&si)[16], int laneq)
{
    constexpr int LX  = M >> 4;    // lane-xor (shuffle mask)
    constexpr int PL  = M & 15;    // local-xor
    constexpr int CML = CM & 15;   // controls in local bits
    constexpr int CMH = CM >> 4;   // controls in lane bits
    float tr[16], ti[16];
#pragma unroll
    for (int i = 0; i < 16; i++) { tr[i] = sr[i]; ti[i] = si[i]; }
#pragma unroll
    for (int i = 0; i < 16; i++) {
        if ((i & CML) == CML) {          // compile-time after unroll
            const int j = i ^ PL;
            float srv = sx<LX>(tr[j]);
            float siv = sx<LX>(ti[j]);
            if constexpr (CMH != 0) {
                const bool c = (laneq & CMH) == CMH;
                sr[i] = c ? srv : sr[i];
                si[i] = c ? siv : si[i];
            } else {
                sr[i] = srv; si[i] = siv;
            }
        }
    }
}

// ---- CSWAP(C; T1,T2) ----
template<int C, int T1, int T2>
__device__ __forceinline__ void applyCSWAP(float (&sr)[16], float (&si)[16], int laneq)
{
    constexpr int M  = (1 << T1) | (1 << T2);
    constexpr int LX = M >> 4;
    constexpr int PL = M & 15;
    float tr[16], ti[16];
#pragma unroll
    for (int i = 0; i < 16; i++) { tr[i] = sr[i]; ti[i] = si[i]; }
#pragma unroll
    for (int i = 0; i < 16; i++) {
        const int g = i | (laneq << 4);
        const bool cnd = (((g >> C) & 1) != 0) && ((((g >> T1) ^ (g >> T2)) & 1) != 0);
        const int j = i ^ PL;
        float srv = sx<LX>(tr[j]);
        float siv = sx<LX>(ti[j]);
        sr[i] = cnd ? srv : sr[i];
        si[i] = cnd ? siv : si[i];
    }
}

// ---- one node step at runtime layer; node N compile-time ----
template<int N>
__device__ __forceinline__ void nodeStep(float (&sr)[16], float (&si)[16], int laneq,
                                         const float (&fc)[8], const float (&fs)[8],
                                         const float* __restrict__ qp,
                                         const int* __restrict__ dry,
                                         const int* __restrict__ drot,
                                         const int* __restrict__ dg2,
                                         int layer)
{
    constexpr int N1 = (N + 1) & 7;
    constexpr int N2 = (N + 2) & 7;
    const int di = layer * 4 + (N & 3);

    // 1) per-sample RY(feats[b, N]) — sincos hoisted
    if (dry[di])
        realGate<N>(sr, si, laneq, fc[N], -fs[N], fs[N], fc[N]);

    // 2) trainable rotation
    const int rot = drot[di];
    if (rot < 3) {
        const float th = qp[layer * NQ + N] * 0.5f;
        const float c = fcosr(th), s = fsinr(th);
        if (rot == 0)      applyRX<N>(sr, si, laneq, c, s);
        else if (rot == 1) realGate<N>(sr, si, laneq, c, -s, s, c);
        else               applyRZ<N>(sr, si, laneq, c, s);
    }

    // 3) entangling / extra gate
    const int g2 = dg2[di];
    switch (g2) {
        case 1: {
            const float r = 0.70710678118654752f;
            realGate<N>(sr, si, laneq, r, r, r, -r);
        } break;
        case 2: applyX<N>(sr, si, laneq); break;
        case 3: applyY<N>(sr, si, laneq); break;
        case 4: applyZ<N>(sr, si, laneq); break;
        case 5: applyCPerm<(1 << N), (1 << N1)>(sr, si, laneq); break;
        case 6: applyCSWAP<N, N1, N2>(sr, si, laneq); break;
        case 7: applyCPerm<(1 << N) | (1 << N1), (1 << N2)>(sr, si, laneq); break;
        case 8: applyCZ<N, N1>(sr, si, laneq); break;
        default: break;
    }
}

__global__ __launch_bounds__(256, 4) void qsim_kernel(
    const float* __restrict__ feats,    // [B, 8]
    const float* __restrict__ qp,       // [48]
    const int* __restrict__ dry,        // [24]
    const int* __restrict__ drot,       // [24]
    const int* __restrict__ dg2,        // [24]
    float* __restrict__ out,            // [B, 8]
    int B)
{
    const int laneq = threadIdx.x & 15;                       // lane within element group
    const int b     = blockIdx.x * 16 + (threadIdx.x >> 4);   // batch element
    if (b >= B) return;

    // per-node half-angle sincos of this element's features
    const float4* f4 = (const float4*)(feats + (size_t)b * NQ);
    float4 fA = f4[0], fB = f4[1];
    const float fv[8] = { fA.x, fA.y, fA.z, fA.w, fB.x, fB.y, fB.z, fB.w };
    float fc[8], fs[8];
#pragma unroll
    for (int k = 0; k < 8; k++) {
        fc[k] = fcosr(fv[k] * 0.5f);
        fs[k] = fsinr(fv[k] * 0.5f);
    }

    // H^8 |0> = uniform amplitude 1/16
    float sr[16], si[16];
#pragma unroll
    for (int i = 0; i < 16; i++) { sr[i] = 0.0625f; si[i] = 0.0f; }

#pragma unroll 1
    for (int layer = 0; layer < 6; layer++) {
        nodeStep<0>(sr, si, laneq, fc, fs, qp, dry, drot, dg2, layer);
        nodeStep<1>(sr, si, laneq, fc, fs, qp, dry, drot, dg2, layer);
        nodeStep<2>(sr, si, laneq, fc, fs, qp, dry, drot, dg2, layer);
        nodeStep<3>(sr, si, laneq, fc, fs, qp, dry, drot, dg2, layer);
        nodeStep<4>(sr, si, laneq, fc, fs, qp, dry, drot, dg2, layer);
        nodeStep<5>(sr, si, laneq, fc, fs, qp, dry, drot, dg2, layer);
        nodeStep<6>(sr, si, laneq, fc, fs, qp, dry, drot, dg2, layer);
        nodeStep<7>(sr, si, laneq, fc, fs, qp, dry, drot, dg2, layer);
    }

    // ---- epilogue: <Z_q> ----
    float p[16];
#pragma unroll
    for (int i = 0; i < 16; i++) p[i] = sr[i] * sr[i] + si[i] * si[i];

    float tot = 0.f;
#pragma unroll
    for (int i = 0; i < 16; i++) tot += p[i];

    float e[4];
#pragma unroll
    for (int q = 0; q < 4; q++) {
        float s0 = 0.f;
#pragma unroll
        for (int i = 0; i < 16; i++) if (!((i >> q) & 1)) s0 += p[i];
        e[q] = 2.f * s0 - tot;           // sum(bit=0) - sum(bit=1)
    }

    // sum e[0..3] over the 16-lane group
#pragma unroll
    for (int q = 0; q < 4; q++) {
        e[q] += sx<1>(e[q]);
        e[q] += sx<2>(e[q]);
        e[q] += sx<4>(e[q]);
        e[q] += sx<8>(e[q]);
    }
    // FWHT on tot: after 4 stages, laneq = (1<<k) holds <Z_{4+k}>
    { float pv = sx<1>(tot); tot = (laneq & 1) ? (pv - tot) : (pv + tot); }
    { float pv = sx<2>(tot); tot = (laneq & 2) ? (pv - tot) : (pv + tot); }
    { float pv = sx<4>(tot); tot = (laneq & 4) ? (pv - tot) : (pv + tot); }
    { float pv = sx<8>(tot); tot = (laneq & 8) ? (pv - tot) : (pv + tot); }

    float* ob = out + (size_t)b * NQ;
    if (laneq == 0)
        *(float4*)ob = make_float4(e[0], e[1], e[2], e[3]);
    if (laneq && !(laneq & (laneq - 1)))          // laneq in {1,2,4,8}
        ob[4 + __builtin_ctz(laneq)] = tot;
}

extern "C" void kernel_launch(void* const* d_in, const int* in_sizes, int n_in,
                              void* d_out, int out_size, void* d_ws, size_t ws_size,
                              hipStream_t stream)
{
    (void)n_in; (void)out_size; (void)d_ws; (void)ws_size;
    const float* feats   = (const float*)d_in[0];
    const float* qparams = (const float*)d_in[1];
    const int* dry       = (const int*)d_in[2];
    const int* drot      = (const int*)d_in[3];
    const int* dg2       = (const int*)d_in[4];
    float* out           = (float*)d_out;

    const int B = in_sizes[0] / NQ;             // 16384
    const int blocks = (B + 15) / 16;           // 16 elements per 256-thread block
    qsim_kernel<<<blocks, 256, 0, stream>>>(feats, qparams, dry, drot, dg2, out, B);
}